// Round 14
// baseline (5459.503 us; speedup 1.0000x reference)
//
#include <hip/hip_runtime.h>

#define DI __device__ __forceinline__

typedef short s16x4 __attribute__((ext_vector_type(4)));
typedef short s16x8 __attribute__((ext_vector_type(8)));
typedef float f32x4 __attribute__((ext_vector_type(4)));

constexpr int CB = 64, CL = 512, CV = 256, CE = 512, CH = 1024;
constexpr int CBL = CB * CL;                // 32768
constexpr size_t LOGN = (size_t)CBL * CV;   // 8388608 floats of logits
constexpr unsigned SLOT = (unsigned)CB * CH * 2;   // 128 KiB per ring slot

// ---- workspace layout (bytes) ----
constexpr size_t WS_BAR   = 0;                              // flags: 4 bgs x 64 ints (1 KiB)
constexpr size_t WS_RING  = 4096;                           // 2-slot ring: 256 KiB
constexpr size_t WS_EMBB  = WS_RING + 2u*SLOT;              // emb bf16   256*512*2
constexpr size_t WS_UWB   = WS_EMBB + (size_t)CV*CE*2;      // U_w bf16   1024*512*2
constexpr size_t WS_VWB   = WS_UWB  + (size_t)CH*CE*2;      // V_w bf16   1024*1024*2
constexpr size_t WS_DECWB = WS_VWB  + (size_t)CH*CH*2;      // dec_w bf16 256*1024*2
constexpr size_t WS_UX    = WS_DECWB+ (size_t)CV*CH*2;      // Ux bf16    32768*1024*2
constexpr size_t WS_HS    = WS_UX   + (size_t)CBL*CH*2;     // hs bf16    32768*1024*2

DI unsigned short f2bf(float f) {            // RNE f32 -> bf16
  unsigned u = __float_as_uint(f);
  u += 0x7FFFu + ((u >> 16) & 1u);
  return (unsigned short)(u >> 16);
}
DI float bf2f(unsigned short h) { return __uint_as_float(((unsigned)h) << 16); }

DI f32x4 mfma_bf16(s16x8 a, s16x8 b, f32x4 c) {
  return __builtin_amdgcn_mfma_f32_16x16x32_bf16(a, b, c, 0, 0, 0);
}

DI float fast_tanh(float x) {
  float a = fminf(fabsf(x), 20.0f);
  float e = __expf(-2.0f * a);
  float r = (1.0f - e) / (1.0f + e);
  return __builtin_copysignf(r, x);
}

// ---------------- convert f32 weights -> bf16 in ws ----------------
__global__ __launch_bounds__(256) void k_convert(
    const float* __restrict__ emb, const float* __restrict__ uw,
    const float* __restrict__ vw,  const float* __restrict__ dw,
    unsigned short* __restrict__ embb, unsigned short* __restrict__ uwb,
    unsigned short* __restrict__ vwb,  unsigned short* __restrict__ dwb)
{
  int i = (blockIdx.x * 256 + threadIdx.x) * 4;   // 1966080 elems total, grid exact
  const float* s; unsigned short* d; int off;
  if      (i < 131072)  { s = emb; d = embb; off = i; }
  else if (i < 655360)  { s = uw;  d = uwb;  off = i - 131072; }
  else if (i < 1703936) { s = vw;  d = vwb;  off = i - 655360; }
  else                  { s = dw;  d = dwb;  off = i - 1703936; }
  float4 v = *(const float4*)(s + off);
  ushort4 o; o.x = f2bf(v.x); o.y = f2bf(v.y); o.z = f2bf(v.z); o.w = f2bf(v.w);
  *(ushort4*)(d + off) = o;
}

// ---------------- generic bf16 MFMA GEMM: C[r, n] = sum_k A[r,k]*B[n,k] ----------------
template<int KD, int NT, bool GATHER, bool OUTF32>
__global__ __launch_bounds__(256) void k_gemm(
    const unsigned short* __restrict__ Asrc,
    const int* __restrict__ xidx,
    const unsigned short* __restrict__ Bsrc,
    const float* __restrict__ biasv,
    unsigned short* __restrict__ Cb,
    float* __restrict__ Cf)
{
  __shared__ unsigned char As[64 * 128];
  __shared__ unsigned char Bs[64 * 128];
  __shared__ int xs[64];

  const int tid = threadIdx.x;
  const int rt = blockIdx.x, ct = blockIdx.y;
  const int r0 = rt * 64, c0 = ct * 64;

  if (GATHER) {
    if (tid < 64) xs[tid] = xidx[r0 + tid];
    __syncthreads();
  }

  const int r  = tid >> 2, kq = tid & 3;
  const unsigned short* aRow = GATHER ? (Asrc + (size_t)xs[r] * KD)
                                      : (Asrc + (size_t)(r0 + r) * KD);
  const unsigned short* bRow = Bsrc + (size_t)(c0 + r) * KD;
  const int dstOff = r * 128 + ((kq * 16) ^ ((r & 7) << 4));

  const int wave = tid >> 6, lane = tid & 63;
  const int ln15 = lane & 15, lg = lane >> 4;
  const int xr = (lane & 7) << 4;
  int aOff[4];
#pragma unroll
  for (int m = 0; m < 4; ++m) aOff[m] = (m * 16 + ln15) * 128 + ((lg * 16) ^ xr);
  const int bOff = (wave * 16 + ln15) * 128 + ((lg * 16) ^ xr);

  f32x4 acc[4] = {};
  for (int kk = 0; kk < KD / 32; ++kk) {
    s16x8 av = *(const s16x8*)(aRow + kk * 32 + kq * 8);
    s16x8 bv = *(const s16x8*)(bRow + kk * 32 + kq * 8);
    __syncthreads();
    *(s16x8*)(As + dstOff) = av;
    *(s16x8*)(Bs + dstOff) = bv;
    __syncthreads();
    s16x8 bf = *(const s16x8*)(Bs + bOff);
#pragma unroll
    for (int m = 0; m < 4; ++m) {
      s16x8 af = *(const s16x8*)(As + aOff[m]);
      acc[m] = mfma_bf16(af, bf, acc[m]);
    }
  }

  const int colg = c0 + wave * 16 + ln15;
  float bv = 0.f;
  if (OUTF32) bv = biasv[colg];
#pragma unroll
  for (int m = 0; m < 4; ++m) {
#pragma unroll
    for (int rr = 0; rr < 4; ++rr) {
      int rowg = r0 + m * 16 + lg * 4 + rr;
      if (OUTF32) Cf[(size_t)rowg * NT + colg] = acc[m][rr] + bv;
      else        Cb[(size_t)rowg * NT + colg] = f2bf(acc[m][rr]);
    }
  }
}

// -------- persistent recurrence, v13: dual-chain software pipeline --------
// 32 wgs x 512 thr. wg b: cs = b>>1 (0..15, 64 cols), pair p = b&1 ->
// chain A = bg 2p, chain B = bg 2p+1 (independent batch-groups).
// Waves 0-3 compute A's cols, waves 4-7 B's; ALL 512 threads stage both slices.
// Per iter: [ds_write A; barrier; A: mfma+pw+produce+drain+flag+hs]
//           [ds_write B; barrier; B: same]
//           [tail: pollA(t+1)+issue stgA; pollB(t+1)+issue stgB]
// -> staging loads in flight a full phase before use; one chain's poll jitter
//    shadowed by the other's compute; ux prefetched 2 iters ahead + hs issued
//    post-flag so the inline vmcnt(0) drains ONLY the 8B produce store.
// Slot-reuse invariant (R10): flag(t-1) is set after the wg-wide barrier that
// joins ALL 8 waves' drains of slot-(t-2) reads -> poll(t-1) proves overwrite
// of slot t&1 safe. Monotonic flags, unconditional barriers: hang-free.
__global__ __launch_bounds__(512, 1) void k_rec(
    const unsigned short* __restrict__ vwb,   // [H][H] bf16
    const unsigned short* __restrict__ ux,    // [B][L][H] bf16
    unsigned short* __restrict__ ring,        // [2][B][H] bf16
    unsigned short* __restrict__ hs,          // [B][L][H] bf16
    const float* __restrict__ alpha, const float* __restrict__ beta1,
    const float* __restrict__ beta2, const float* __restrict__ bias,
    float* __restrict__ out, int* flags)
{
  __shared__ __align__(16) unsigned char ldsA[16 * 2048];   // 32 KiB: A h-slice
  __shared__ __align__(16) unsigned char ldsB[16 * 2048];   // 32 KiB: B h-slice

  const int bid = blockIdx.x;
  const int cs = bid >> 1, pair = bid & 1;
  const int bgA = pair * 2, bgB = pair * 2 + 1;
  const int tid = threadIdx.x;
  const int wave = tid >> 6, lane = tid & 63;
  const int ln15 = lane & 15, lg = lane >> 4;
  const bool isA = (wave < 4);
  const int w4 = wave & 3;
  const int mybg = isA ? bgA : bgB;
  const int myb = mybg * 16 + ln15;                 // my batch (swapped-MFMA D col)
  const int colbase = cs * 64 + w4 * 16 + lg * 4;   // my 4 contiguous V-cols

  // A-operand resident: V_w rows = my wave's 16 cols (shared across bgs)
  s16x8 breg[32];
  {
    const unsigned short* vrow = vwb + (size_t)(cs * 64 + w4 * 16 + ln15) * CH + lg * 8;
#pragma unroll
    for (int kc = 0; kc < 32; ++kc) breg[kc] = *(const s16x8*)(vrow + kc * 32);
  }
#pragma unroll
  for (int kc = 0; kc < 32; ++kc) asm volatile("" : "+v"(breg[kc]));  // pin (R5)

  const float4 alv = *(const float4*)(alpha + colbase);
  const float4 b1v = *(const float4*)(beta1 + colbase);
  const float4 b2v = *(const float4*)(beta2 + colbase);
  const float4 biv = *(const float4*)(bias  + colbase);

  __amdgpu_buffer_rsrc_t rsrd = __builtin_amdgcn_make_buffer_rsrc(
      (void*)ring, (short)0, (int)(2u * SLOT), 0x00020000);

  int* pfA = flags + bgA * 64;     // 64 producer-wave flags per bg
  int* pfB = flags + bgB * 64;
  int* myf = flags + mybg * 64 + (cs * 4 + w4);

  // staging geometry (R12-validated, conflict-free): thread stages 4 x 16B / slice
  int sRow[4], sCol[4];
#pragma unroll
  for (int i = 0; i < 4; ++i) {
    const int L = i * 8192 + tid * 16;
    sRow[i] = L >> 11;
    sCol[i] = (L & 2047) ^ ((sRow[i] & 15) << 4);
  }
  const unsigned baseA = (unsigned)(bgA * 16 * 2048);
  const unsigned baseB = (unsigned)(bgB * 16 * 2048);

  const int fBase = ln15 * 2048;
  const int fXor  = ln15 << 4;
  const unsigned cellOff = (unsigned)(myb * 2048 + colbase * 2);

  auto pollwait = [&](int* pf, int target) {
    bool ok;
    do {
      int v = __hip_atomic_load(&pf[lane], __ATOMIC_RELAXED, __HIP_MEMORY_SCOPE_SYSTEM);
      ok = __all(v >= target) != 0;
    } while (!ok);
    asm volatile("" ::: "memory");
  };
  auto issue_stg = [&](s16x8* dst, unsigned roff) {
#pragma unroll
    for (int i = 0; i < 4; ++i) {
      auto raw = __builtin_amdgcn_raw_buffer_load_b128(
          rsrd, (int)(roff + i * 8192 + tid * 16), 0, 17);
      dst[i] = __builtin_bit_cast(s16x8, raw);
    }
  };
  auto lds_write = [&](unsigned char* lb, const s16x8* src) {
#pragma unroll
    for (int i = 0; i < 4; ++i)
      *(s16x8*)(lb + sRow[i] * 2048 + sCol[i]) = src[i];
  };
  auto do_mfma = [&](const unsigned char* lb) {
    f32x4 a0 = {}, a1 = {}, a2 = {}, a3 = {};
#pragma unroll
    for (int kc = 0; kc < 32; kc += 4) {
      s16x8 f0 = *(const s16x8*)(lb + fBase + ((lg * 16 + kc * 64)       ^ fXor));
      s16x8 f1 = *(const s16x8*)(lb + fBase + ((lg * 16 + kc * 64 + 64)  ^ fXor));
      s16x8 f2 = *(const s16x8*)(lb + fBase + ((lg * 16 + kc * 64 + 128) ^ fXor));
      s16x8 f3 = *(const s16x8*)(lb + fBase + ((lg * 16 + kc * 64 + 192) ^ fXor));
      a0 = mfma_bf16(breg[kc],     f0, a0);
      a1 = mfma_bf16(breg[kc + 1], f1, a1);
      a2 = mfma_bf16(breg[kc + 2], f2, a2);
      a3 = mfma_bf16(breg[kc + 3], f3, a3);
    }
    return (a0 + a1) + (a2 + a3);
  };
  auto pointwise = [&](f32x4 vh, const s16x4& uxv, float* hnv, unsigned short* hbv) {
#pragma unroll
    for (int rr = 0; rr < 4; ++rr) {
      const float u = bf2f((unsigned short)uxv[rr]);
      const float v = vh[rr];
      const float mm = (&alv.x)[rr] * (v * u) + (&b1v.x)[rr] * v +
                       (&b2v.x)[rr] * u + (&biv.x)[rr];
      hnv[rr] = fast_tanh(mm);
      hbv[rr] = f2bf(hnv[rr]);
    }
  };
  auto uxaddr = [&](int t) { return (const s16x4*)(ux + ((size_t)myb * CL + t) * CH + colbase); };

  // ux 2-ahead pipeline
  s16x4 ux_c = *uxaddr(0), ux_1 = *uxaddr(1), ux_2 = *uxaddr(2);

  s16x8 stgA[4], stgB[4];

  // ---- prologue: t = 0 (vh = 0) ----
  {
    float hnv[4]; unsigned short hbv[4];
    pointwise(f32x4{}, ux_c, hnv, hbv);
    const unsigned long long pk = (unsigned long long)hbv[0]
                                | ((unsigned long long)hbv[1] << 16)
                                | ((unsigned long long)hbv[2] << 32)
                                | ((unsigned long long)hbv[3] << 48);
    __hip_atomic_store((unsigned long long*)((char*)ring + cellOff), pk,
                       __ATOMIC_RELAXED, __HIP_MEMORY_SCOPE_SYSTEM);
    asm volatile("s_waitcnt vmcnt(0)" ::: "memory");
    if (lane == 0)
      __hip_atomic_store(myf, 1, __ATOMIC_RELAXED, __HIP_MEMORY_SCOPE_SYSTEM);
    *(unsigned long long*)(hs + ((size_t)myb * CL + 0) * CH + colbase) = pk;
    pollwait(pfA, 1); issue_stg(stgA, baseA);
    pollwait(pfB, 1); issue_stg(stgB, baseB);
  }

  for (int t = 1; t < CL; ++t) {
    // ux shift: ux_c becomes ux(t); issue ux(t+2)
    ux_c = ux_1; ux_1 = ux_2;
    if (t + 2 < CL) ux_2 = *uxaddr(t + 2);

    // ===== phase A =====
    lds_write(ldsA, stgA);                 // compiler waits exact vmcnt for stgA
    __syncthreads();
    if (isA) {
      f32x4 vh = do_mfma(ldsA);
      float hnv[4]; unsigned short hbv[4];
      pointwise(vh, ux_c, hnv, hbv);
      const unsigned long long pk = (unsigned long long)hbv[0]
                                  | ((unsigned long long)hbv[1] << 16)
                                  | ((unsigned long long)hbv[2] << 32)
                                  | ((unsigned long long)hbv[3] << 48);
      if (t < CL - 1) {
        __hip_atomic_store((unsigned long long*)
            ((char*)ring + (size_t)(t & 1) * SLOT + cellOff), pk,
            __ATOMIC_RELAXED, __HIP_MEMORY_SCOPE_SYSTEM);
        asm volatile("s_waitcnt vmcnt(0)" ::: "memory");   // drains produce only
        if (lane == 0)
          __hip_atomic_store(myf, t + 1, __ATOMIC_RELAXED, __HIP_MEMORY_SCOPE_SYSTEM);
        *(unsigned long long*)(hs + ((size_t)myb * CL + t) * CH + colbase) = pk;
      } else {
        *(unsigned long long*)(hs + ((size_t)myb * CL + t) * CH + colbase) = pk;
        float4 o; o.x = hnv[0]; o.y = hnv[1]; o.z = hnv[2]; o.w = hnv[3];
        *(float4*)(out + LOGN + (size_t)myb * CH + colbase) = o;
      }
    }

    // ===== phase B =====
    lds_write(ldsB, stgB);
    __syncthreads();
    if (!isA) {
      f32x4 vh = do_mfma(ldsB);
      float hnv[4]; unsigned short hbv[4];
      pointwise(vh, ux_c, hnv, hbv);
      const unsigned long long pk = (unsigned long long)hbv[0]
                                  | ((unsigned long long)hbv[1] << 16)
                                  | ((unsigned long long)hbv[2] << 32)
                                  | ((unsigned long long)hbv[3] << 48);
      if (t < CL - 1) {
        __hip_atomic_store((unsigned long long*)
            ((char*)ring + (size_t)(t & 1) * SLOT + cellOff), pk,
            __ATOMIC_RELAXED, __HIP_MEMORY_SCOPE_SYSTEM);
        asm volatile("s_waitcnt vmcnt(0)" ::: "memory");
        if (lane == 0)
          __hip_atomic_store(myf, t + 1, __ATOMIC_RELAXED, __HIP_MEMORY_SCOPE_SYSTEM);
        *(unsigned long long*)(hs + ((size_t)myb * CL + t) * CH + colbase) = pk;
      } else {
        *(unsigned long long*)(hs + ((size_t)myb * CL + t) * CH + colbase) = pk;
        float4 o; o.x = hnv[0]; o.y = hnv[1]; o.z = hnv[2]; o.w = hnv[3];
        *(float4*)(out + LOGN + (size_t)myb * CH + colbase) = o;
      }
    }

    // ===== tail: prefetch next iter's slices (loads fly across the loop-back) =====
    if (t < CL - 1) {
      const unsigned so = (unsigned)(t & 1) * SLOT;
      pollwait(pfA, t + 1); issue_stg(stgA, so + baseA);
      pollwait(pfB, t + 1); issue_stg(stgB, so + baseB);
    }
  }
}

extern "C" void kernel_launch(void* const* d_in, const int* in_sizes, int n_in,
                              void* d_out, int out_size, void* d_ws, size_t ws_size,
                              hipStream_t stream) {
  const int*   x     = (const int*)  d_in[0];
  const float* emb   = (const float*)d_in[1];
  const float* Uw    = (const float*)d_in[2];
  const float* Vw    = (const float*)d_in[3];
  const float* alpha = (const float*)d_in[4];
  const float* beta1 = (const float*)d_in[5];
  const float* beta2 = (const float*)d_in[6];
  const float* bias  = (const float*)d_in[7];
  const float* decw  = (const float*)d_in[8];
  const float* decb  = (const float*)d_in[9];
  float* out = (float*)d_out;
  char*  ws  = (char*)d_ws;

  int*            flags = (int*)(ws + WS_BAR);
  unsigned short* ring  = (unsigned short*)(ws + WS_RING);
  unsigned short* embb  = (unsigned short*)(ws + WS_EMBB);
  unsigned short* uwb   = (unsigned short*)(ws + WS_UWB);
  unsigned short* vwb   = (unsigned short*)(ws + WS_VWB);
  unsigned short* dwb   = (unsigned short*)(ws + WS_DECWB);
  unsigned short* uxb   = (unsigned short*)(ws + WS_UX);
  unsigned short* hsb   = (unsigned short*)(ws + WS_HS);

  (void)hipMemsetAsync(ws + WS_BAR, 0, 1024, stream);   // epoch flags = 0

  k_convert<<<1920, 256, 0, stream>>>(emb, Uw, Vw, decw, embb, uwb, vwb, dwb);

  k_gemm<CE, CH, true, false><<<dim3(CBL / 64, CH / 64), 256, 0, stream>>>(
      embb, x, uwb, nullptr, uxb, nullptr);

  k_rec<<<32, 512, 0, stream>>>(vwb, uxb, ring, hsb, alpha, beta1, beta2, bias,
                                out, flags);

  k_gemm<CH, CV, false, true><<<dim3(CBL / 64, CV / 64), 256, 0, stream>>>(
      hsb, nullptr, dwb, decb, nullptr, out);
}

// Round 16
// 3217.686 us; speedup vs baseline: 1.6967x; 1.6967x over previous
//
#include <hip/hip_runtime.h>

#define DI __device__ __forceinline__

typedef short s16x4 __attribute__((ext_vector_type(4)));
typedef short s16x8 __attribute__((ext_vector_type(8)));
typedef float f32x4 __attribute__((ext_vector_type(4)));

constexpr int CB = 64, CL = 512, CV = 256, CE = 512, CH = 1024;
constexpr int CBL = CB * CL;                // 32768
constexpr size_t LOGN = (size_t)CBL * CV;   // 8388608 floats of logits
constexpr unsigned SLOT = (unsigned)CB * CH * 2;   // 128 KiB per ring slot

// ---- workspace layout (bytes) ----
constexpr size_t WS_BAR   = 0;                              // flags: 4 bgs x 64 ints (1 KiB)
constexpr size_t WS_XCDT  = 1024;                           // xcd table: 4 x 16 ints
constexpr size_t WS_RING  = 4096;                           // 2-slot ring: 256 KiB
constexpr size_t WS_EMBB  = WS_RING + 2u*SLOT;              // emb bf16   256*512*2
constexpr size_t WS_UWB   = WS_EMBB + (size_t)CV*CE*2;      // U_w bf16   1024*512*2
constexpr size_t WS_VWB   = WS_UWB  + (size_t)CH*CE*2;      // V_w bf16   1024*1024*2
constexpr size_t WS_DECWB = WS_VWB  + (size_t)CH*CH*2;      // dec_w bf16 256*1024*2
constexpr size_t WS_UX    = WS_DECWB+ (size_t)CV*CH*2;      // Ux bf16    32768*1024*2
constexpr size_t WS_HS    = WS_UX   + (size_t)CBL*CH*2;     // hs bf16    32768*1024*2

DI unsigned short f2bf(float f) {            // RNE f32 -> bf16
  unsigned u = __float_as_uint(f);
  u += 0x7FFFu + ((u >> 16) & 1u);
  return (unsigned short)(u >> 16);
}
DI float bf2f(unsigned short h) { return __uint_as_float(((unsigned)h) << 16); }

DI f32x4 mfma_bf16(s16x8 a, s16x8 b, f32x4 c) {
  return __builtin_amdgcn_mfma_f32_16x16x32_bf16(a, b, c, 0, 0, 0);
}

DI float fast_tanh(float x) {
  float a = fminf(fabsf(x), 20.0f);
  float e = __expf(-2.0f * a);
  float r = (1.0f - e) / (1.0f + e);
  return __builtin_copysignf(r, x);
}

// ---------------- convert f32 weights -> bf16 in ws ----------------
__global__ __launch_bounds__(256) void k_convert(
    const float* __restrict__ emb, const float* __restrict__ uw,
    const float* __restrict__ vw,  const float* __restrict__ dw,
    unsigned short* __restrict__ embb, unsigned short* __restrict__ uwb,
    unsigned short* __restrict__ vwb,  unsigned short* __restrict__ dwb)
{
  int i = (blockIdx.x * 256 + threadIdx.x) * 4;   // 1966080 elems total, grid exact
  const float* s; unsigned short* d; int off;
  if      (i < 131072)  { s = emb; d = embb; off = i; }
  else if (i < 655360)  { s = uw;  d = uwb;  off = i - 131072; }
  else if (i < 1703936) { s = vw;  d = vwb;  off = i - 655360; }
  else                  { s = dw;  d = dwb;  off = i - 1703936; }
  float4 v = *(const float4*)(s + off);
  ushort4 o; o.x = f2bf(v.x); o.y = f2bf(v.y); o.z = f2bf(v.z); o.w = f2bf(v.w);
  *(ushort4*)(d + off) = o;
}

// ---------------- generic bf16 MFMA GEMM: C[r, n] = sum_k A[r,k]*B[n,k] ----------------
template<int KD, int NT, bool GATHER, bool OUTF32>
__global__ __launch_bounds__(256) void k_gemm(
    const unsigned short* __restrict__ Asrc,
    const int* __restrict__ xidx,
    const unsigned short* __restrict__ Bsrc,
    const float* __restrict__ biasv,
    unsigned short* __restrict__ Cb,
    float* __restrict__ Cf)
{
  __shared__ unsigned char As[64 * 128];
  __shared__ unsigned char Bs[64 * 128];
  __shared__ int xs[64];

  const int tid = threadIdx.x;
  const int rt = blockIdx.x, ct = blockIdx.y;
  const int r0 = rt * 64, c0 = ct * 64;

  if (GATHER) {
    if (tid < 64) xs[tid] = xidx[r0 + tid];
    __syncthreads();
  }

  const int r  = tid >> 2, kq = tid & 3;
  const unsigned short* aRow = GATHER ? (Asrc + (size_t)xs[r] * KD)
                                      : (Asrc + (size_t)(r0 + r) * KD);
  const unsigned short* bRow = Bsrc + (size_t)(c0 + r) * KD;
  const int dstOff = r * 128 + ((kq * 16) ^ ((r & 7) << 4));

  const int wave = tid >> 6, lane = tid & 63;
  const int ln15 = lane & 15, lg = lane >> 4;
  const int xr = (lane & 7) << 4;
  int aOff[4];
#pragma unroll
  for (int m = 0; m < 4; ++m) aOff[m] = (m * 16 + ln15) * 128 + ((lg * 16) ^ xr);
  const int bOff = (wave * 16 + ln15) * 128 + ((lg * 16) ^ xr);

  f32x4 acc[4] = {};
  for (int kk = 0; kk < KD / 32; ++kk) {
    s16x8 av = *(const s16x8*)(aRow + kk * 32 + kq * 8);
    s16x8 bv = *(const s16x8*)(bRow + kk * 32 + kq * 8);
    __syncthreads();
    *(s16x8*)(As + dstOff) = av;
    *(s16x8*)(Bs + dstOff) = bv;
    __syncthreads();
    s16x8 bf = *(const s16x8*)(Bs + bOff);
#pragma unroll
    for (int m = 0; m < 4; ++m) {
      s16x8 af = *(const s16x8*)(As + aOff[m]);
      acc[m] = mfma_bf16(af, bf, acc[m]);
    }
  }

  const int colg = c0 + wave * 16 + ln15;
  float bv = 0.f;
  if (OUTF32) bv = biasv[colg];
#pragma unroll
  for (int m = 0; m < 4; ++m) {
#pragma unroll
    for (int rr = 0; rr < 4; ++rr) {
      int rowg = r0 + m * 16 + lg * 4 + rr;
      if (OUTF32) Cf[(size_t)rowg * NT + colg] = acc[m][rr] + bv;
      else        Cb[(size_t)rowg * NT + colg] = f2bf(acc[m][rr]);
    }
  }
}

struct FastTag { static constexpr bool fast = true;  };
struct SafeTag { static constexpr bool fast = false; };

// ---- persistent recurrence, v15: R12 (proven best) + 4-step hs/ux batching ----
// 64 wgs x 512 thr; role: bg=bid&7 (<4 else exit), cs=bid>>3 (128 cols).
// Protocol = R12 exactly (7x hang-free): per-wave monotonic epoch flags;
// produce 8B -> vmcnt(0) [drains produce only] -> lane0 flag; consumers
// busy-poll 64 flags lane-parallel. FAST (sc0/AGENT, XCD-L2) after
// registration check, else SAFE (sc0sc1/SYSTEM, L3).
// v15 change: hs stores + ux loads batched 4 steps (issued after the 4th
// step's flag) -> vmcnt pollution of the poll (in-order counter waiting on
// the ~900cy HBM ux load) happens once per 4 steps instead of every step.
// t-loop unrolled x4 with NAMED pk/ux registers (no runtime-indexed arrays).
__global__ __launch_bounds__(512, 1) void k_rec(
    const unsigned short* __restrict__ vwb,   // [H][H] bf16
    const unsigned short* __restrict__ ux,    // [B][L][H] bf16
    unsigned short* __restrict__ ring,        // [2][B][H] bf16
    unsigned short* __restrict__ hs,          // [B][L][H] bf16
    const float* __restrict__ alpha, const float* __restrict__ beta1,
    const float* __restrict__ beta2, const float* __restrict__ bias,
    float* __restrict__ out, int* flags, int* xcdtab)
{
  __shared__ __align__(16) unsigned char hlds[2][16 * 2048];   // 2 x 32 KiB
  __shared__ int smode;

  const int bid = blockIdx.x;
  const int bg = bid & 7, cs = bid >> 3;    // batch-group, col-slice (128 cols)
  if (bg >= 4) return;                      // spare wgs exit
  const int tid = threadIdx.x;
  const int wave = tid >> 6, lane = tid & 63;
  const int ln15 = lane & 15, lg = lane >> 4;
  const int b0 = bg * 16;
  const int colbase = cs * 128 + wave * 16 + lg * 4;
  const int myb = b0 + ln15;

  // ---- one-time registration + mode select ----
  int* gxt = xcdtab + bg * 16;
  if (tid == 0) {
    unsigned myxcd;
    asm volatile("s_getreg_b32 %0, hwreg(HW_REG_XCC_ID)" : "=s"(myxcd));
    myxcd &= 15u;
    __hip_atomic_store(&gxt[cs], (int)myxcd, __ATOMIC_RELAXED, __HIP_MEMORY_SCOPE_SYSTEM);
    int first = -1; bool same = true;
    for (int i = 0; i < 8;) {
      int v = __hip_atomic_load(&gxt[i], __ATOMIC_RELAXED, __HIP_MEMORY_SCOPE_SYSTEM);
      if (v == -1) { __builtin_amdgcn_s_sleep(8); continue; }
      if (first == -1) first = v; else if (v != first) same = false;
      ++i;
    }
    smode = same ? 1 : 0;
  }
  __syncthreads();
  const bool fastmode = (smode != 0);

  // A-operand resident: breg[kc] lane l = V_w[colrow][kc*32+(l>>4)*8..+8]
  s16x8 breg[32];
  {
    const unsigned short* vrow = vwb + (size_t)(cs * 128 + wave * 16 + ln15) * CH + lg * 8;
#pragma unroll
    for (int kc = 0; kc < 32; ++kc) breg[kc] = *(const s16x8*)(vrow + kc * 32);
  }
#pragma unroll
  for (int kc = 0; kc < 32; ++kc) asm volatile("" : "+v"(breg[kc]));  // pin (R5)

  const float4 alv = *(const float4*)(alpha + colbase);
  const float4 b1v = *(const float4*)(beta1 + colbase);
  const float4 b2v = *(const float4*)(beta2 + colbase);
  const float4 biv = *(const float4*)(bias  + colbase);

  __amdgpu_buffer_rsrc_t rsrd = __builtin_amdgcn_make_buffer_rsrc(
      (void*)ring, (short)0, (int)(2u * SLOT), 0x00020000);

  int* gflags = flags + bg * 64;            // 64 wave-flags per group (8 wgs x 8 waves)
  const int myflag = cs * 8 + wave;

  // staging: 512 threads x 4 chunks x 16B = 32 KiB slice (R12, conflict-free)
  int sRow[4], sCol[4];
#pragma unroll
  for (int i = 0; i < 4; ++i) {
    const int L = i * 8192 + tid * 16;
    sRow[i] = L >> 11;
    sCol[i] = (L & 2047) ^ ((sRow[i] & 15) << 4);
  }
  const unsigned stgBase = (unsigned)(b0 * 2048);

  const int fBase = ln15 * 2048;
  const int fXor  = ln15 << 4;
  const unsigned cellOff = (unsigned)(myb * 2048 + colbase * 2);

  auto uxaddr = [&](int t) {
    return (const s16x4*)(ux + ((size_t)myb * CL + t) * CH + colbase);
  };

  auto run = [&](auto tag) {
    constexpr int  AUX = decltype(tag)::fast ? 1 : 17;
    constexpr auto SCP = decltype(tag)::fast ? __HIP_MEMORY_SCOPE_AGENT
                                             : __HIP_MEMORY_SCOPE_SYSTEM;

    auto step = [&](int t, const s16x4& uxv, unsigned long long& pkv,
                    float* hnv) {
      f32x4 vh = {};
      if (t > 0) {
        // busy-poll all 64 producer-wave flags, lane-parallel
        bool ok;
        do {
          int fv = __hip_atomic_load(&gflags[lane], __ATOMIC_RELAXED, SCP);
          ok = __all(fv >= t) != 0;
        } while (!ok);
        asm volatile("" ::: "memory");

        // stage h(t-1) slice from slot (t-1)&1 into LDS (4 chunks/thread)
        const unsigned roff = ((unsigned)((t - 1) & 1)) * SLOT + stgBase;
        s16x8 stg[4];
#pragma unroll
        for (int i = 0; i < 4; ++i) {
          auto raw = __builtin_amdgcn_raw_buffer_load_b128(
              rsrd, (int)(roff + i * 8192 + tid * 16), 0, AUX);
          stg[i] = __builtin_bit_cast(s16x8, raw);
        }
        unsigned char* lb = hlds[t & 1];
#pragma unroll
        for (int i = 0; i < 4; ++i)
          *(s16x8*)(lb + sRow[i] * 2048 + sCol[i]) = stg[i];
        __syncthreads();                    // the ONE join per step

        // fragments + MFMA, A=V_w (resident), B=h, 4 chains
        f32x4 a0 = {}, a1 = {}, a2 = {}, a3 = {};
#pragma unroll
        for (int kc = 0; kc < 32; kc += 4) {
          s16x8 f0 = *(const s16x8*)(lb + fBase + ((lg * 16 + kc * 64)       ^ fXor));
          s16x8 f1 = *(const s16x8*)(lb + fBase + ((lg * 16 + kc * 64 + 64)  ^ fXor));
          s16x8 f2 = *(const s16x8*)(lb + fBase + ((lg * 16 + kc * 64 + 128) ^ fXor));
          s16x8 f3 = *(const s16x8*)(lb + fBase + ((lg * 16 + kc * 64 + 192) ^ fXor));
          a0 = mfma_bf16(breg[kc],     f0, a0);
          a1 = mfma_bf16(breg[kc + 1], f1, a1);
          a2 = mfma_bf16(breg[kc + 2], f2, a2);
          a3 = mfma_bf16(breg[kc + 3], f3, a3);
        }
        vh = (a0 + a1) + (a2 + a3);
      }

      // pointwise
      unsigned short hbv[4];
#pragma unroll
      for (int rr = 0; rr < 4; ++rr) {
        const float u = bf2f((unsigned short)uxv[rr]);
        const float v = vh[rr];
        const float mm = (&alv.x)[rr] * (v * u) + (&b1v.x)[rr] * v +
                         (&b2v.x)[rr] * u + (&biv.x)[rr];
        hnv[rr] = fast_tanh(mm);
        hbv[rr] = f2bf(hnv[rr]);
      }
      pkv = (unsigned long long)hbv[0]
          | ((unsigned long long)hbv[1] << 16)
          | ((unsigned long long)hbv[2] << 32)
          | ((unsigned long long)hbv[3] << 48);

      if (t < CL - 1) {
        // produce: ONE 8B store into slot t&1
        __hip_atomic_store((unsigned long long*)
            ((char*)ring + (size_t)(t & 1) * SLOT + cellOff), pkv,
            __ATOMIC_RELAXED, SCP);
        // wave-level release: drain produce ONLY, then publish wave flag
        asm volatile("s_waitcnt vmcnt(0)" ::: "memory");
        if (lane == 0)
          __hip_atomic_store(&gflags[myflag], t + 1, __ATOMIC_RELAXED, SCP);
      }
    };

    // ux prefetch registers for the current 4-step group (named, static)
    s16x4 ux0 = *uxaddr(0), ux1 = *uxaddr(1), ux2 = *uxaddr(2), ux3 = *uxaddr(3);
    unsigned long long pk0, pk1, pk2, pk3;
    float hn0[4], hn1[4], hn2[4], hn3[4];

    for (int tb = 0; tb < CL; tb += 4) {
      step(tb + 0, ux0, pk0, hn0);
      step(tb + 1, ux1, pk1, hn1);
      step(tb + 2, ux2, pk2, hn2);
      step(tb + 3, ux3, pk3, hn3);

      // ---- batched off-critical-path IO (after flags; pollutes poll 1x/4) ----
      *(unsigned long long*)(hs + ((size_t)myb * CL + tb + 0) * CH + colbase) = pk0;
      *(unsigned long long*)(hs + ((size_t)myb * CL + tb + 1) * CH + colbase) = pk1;
      *(unsigned long long*)(hs + ((size_t)myb * CL + tb + 2) * CH + colbase) = pk2;
      *(unsigned long long*)(hs + ((size_t)myb * CL + tb + 3) * CH + colbase) = pk3;
      if (tb + 4 < CL) {
        ux0 = *uxaddr(tb + 4); ux1 = *uxaddr(tb + 5);
        ux2 = *uxaddr(tb + 6); ux3 = *uxaddr(tb + 7);
      }
    }
    // final-h output (t = CL-1 values live in hn3)
    {
      float4 o; o.x = hn3[0]; o.y = hn3[1]; o.z = hn3[2]; o.w = hn3[3];
      *(float4*)(out + LOGN + (size_t)myb * CH + colbase) = o;
    }
  };
  if (fastmode) run(FastTag{}); else run(SafeTag{});
}

extern "C" void kernel_launch(void* const* d_in, const int* in_sizes, int n_in,
                              void* d_out, int out_size, void* d_ws, size_t ws_size,
                              hipStream_t stream) {
  const int*   x     = (const int*)  d_in[0];
  const float* emb   = (const float*)d_in[1];
  const float* Uw    = (const float*)d_in[2];
  const float* Vw    = (const float*)d_in[3];
  const float* alpha = (const float*)d_in[4];
  const float* beta1 = (const float*)d_in[5];
  const float* beta2 = (const float*)d_in[6];
  const float* bias  = (const float*)d_in[7];
  const float* decw  = (const float*)d_in[8];
  const float* decb  = (const float*)d_in[9];
  float* out = (float*)d_out;
  char*  ws  = (char*)d_ws;

  int*            flags = (int*)(ws + WS_BAR);
  int*            xcdt  = (int*)(ws + WS_XCDT);
  unsigned short* ring  = (unsigned short*)(ws + WS_RING);
  unsigned short* embb  = (unsigned short*)(ws + WS_EMBB);
  unsigned short* uwb   = (unsigned short*)(ws + WS_UWB);
  unsigned short* vwb   = (unsigned short*)(ws + WS_VWB);
  unsigned short* dwb   = (unsigned short*)(ws + WS_DECWB);
  unsigned short* uxb   = (unsigned short*)(ws + WS_UX);
  unsigned short* hsb   = (unsigned short*)(ws + WS_HS);

  (void)hipMemsetAsync(ws + WS_BAR, 0, 1024, stream);        // epoch flags = 0
  (void)hipMemsetAsync(ws + WS_XCDT, 0xFF, 256, stream);     // xcd table = -1

  k_convert<<<1920, 256, 0, stream>>>(emb, Uw, Vw, decw, embb, uwb, vwb, dwb);

  k_gemm<CE, CH, true, false><<<dim3(CBL / 64, CH / 64), 256, 0, stream>>>(
      embb, x, uwb, nullptr, uxb, nullptr);

  k_rec<<<64, 512, 0, stream>>>(vwb, uxb, ring, hsb, alpha, beta1, beta2, bias,
                                out, flags, xcdt);

  k_gemm<CH, CV, false, true><<<dim3(CBL / 64, CV / 64), 256, 0, stream>>>(
      hsb, nullptr, dwb, decb, nullptr, out);
}

// Round 17
// 1650.236 us; speedup vs baseline: 3.3083x; 1.9498x over previous
//
#include <hip/hip_runtime.h>

#define DI __device__ __forceinline__

typedef short s16x4 __attribute__((ext_vector_type(4)));
typedef short s16x8 __attribute__((ext_vector_type(8)));
typedef float f32x4 __attribute__((ext_vector_type(4)));

constexpr int CB = 64, CL = 512, CV = 256, CE = 512, CH = 1024;
constexpr int CBL = CB * CL;                // 32768
constexpr size_t LOGN = (size_t)CBL * CV;   // 8388608 floats of logits
constexpr unsigned SLOT = (unsigned)CB * CH * 2;   // 128 KiB per ring slot

// ---- workspace layout (bytes) ----
constexpr size_t WS_BAR   = 0;                              // flags: 4 bgs x 64 ints (1 KiB)
constexpr size_t WS_XCDT  = 1024;                           // xcd table: 4 x 16 ints
constexpr size_t WS_RING  = 4096;                           // 2-slot ring: 256 KiB
constexpr size_t WS_EMBB  = WS_RING + 2u*SLOT;              // emb bf16   256*512*2
constexpr size_t WS_UWB   = WS_EMBB + (size_t)CV*CE*2;      // U_w bf16   1024*512*2
constexpr size_t WS_VWB   = WS_UWB  + (size_t)CH*CE*2;      // V_w bf16   1024*1024*2
constexpr size_t WS_DECWB = WS_VWB  + (size_t)CH*CH*2;      // dec_w bf16 256*1024*2
constexpr size_t WS_UX    = WS_DECWB+ (size_t)CV*CH*2;      // Ux bf16    32768*1024*2
constexpr size_t WS_HS    = WS_UX   + (size_t)CBL*CH*2;     // hs bf16    32768*1024*2

DI unsigned short f2bf(float f) {            // RNE f32 -> bf16
  unsigned u = __float_as_uint(f);
  u += 0x7FFFu + ((u >> 16) & 1u);
  return (unsigned short)(u >> 16);
}
DI float bf2f(unsigned short h) { return __uint_as_float(((unsigned)h) << 16); }

DI f32x4 mfma_bf16(s16x8 a, s16x8 b, f32x4 c) {
  return __builtin_amdgcn_mfma_f32_16x16x32_bf16(a, b, c, 0, 0, 0);
}

DI float fast_tanh(float x) {
  float a = fminf(fabsf(x), 20.0f);
  float e = __expf(-2.0f * a);
  float r = (1.0f - e) / (1.0f + e);
  return __builtin_copysignf(r, x);
}

// ---------------- convert f32 weights -> bf16 in ws ----------------
__global__ __launch_bounds__(256) void k_convert(
    const float* __restrict__ emb, const float* __restrict__ uw,
    const float* __restrict__ vw,  const float* __restrict__ dw,
    unsigned short* __restrict__ embb, unsigned short* __restrict__ uwb,
    unsigned short* __restrict__ vwb,  unsigned short* __restrict__ dwb)
{
  int i = (blockIdx.x * 256 + threadIdx.x) * 4;   // 1966080 elems total, grid exact
  const float* s; unsigned short* d; int off;
  if      (i < 131072)  { s = emb; d = embb; off = i; }
  else if (i < 655360)  { s = uw;  d = uwb;  off = i - 131072; }
  else if (i < 1703936) { s = vw;  d = vwb;  off = i - 655360; }
  else                  { s = dw;  d = dwb;  off = i - 1703936; }
  float4 v = *(const float4*)(s + off);
  ushort4 o; o.x = f2bf(v.x); o.y = f2bf(v.y); o.z = f2bf(v.z); o.w = f2bf(v.w);
  *(ushort4*)(d + off) = o;
}

// ---------------- generic bf16 MFMA GEMM: C[r, n] = sum_k A[r,k]*B[n,k] ----------------
template<int KD, int NT, bool GATHER, bool OUTF32>
__global__ __launch_bounds__(256) void k_gemm(
    const unsigned short* __restrict__ Asrc,
    const int* __restrict__ xidx,
    const unsigned short* __restrict__ Bsrc,
    const float* __restrict__ biasv,
    unsigned short* __restrict__ Cb,
    float* __restrict__ Cf)
{
  __shared__ unsigned char As[64 * 128];
  __shared__ unsigned char Bs[64 * 128];
  __shared__ int xs[64];

  const int tid = threadIdx.x;
  const int rt = blockIdx.x, ct = blockIdx.y;
  const int r0 = rt * 64, c0 = ct * 64;

  if (GATHER) {
    if (tid < 64) xs[tid] = xidx[r0 + tid];
    __syncthreads();
  }

  const int r  = tid >> 2, kq = tid & 3;
  const unsigned short* aRow = GATHER ? (Asrc + (size_t)xs[r] * KD)
                                      : (Asrc + (size_t)(r0 + r) * KD);
  const unsigned short* bRow = Bsrc + (size_t)(c0 + r) * KD;
  const int dstOff = r * 128 + ((kq * 16) ^ ((r & 7) << 4));

  const int wave = tid >> 6, lane = tid & 63;
  const int ln15 = lane & 15, lg = lane >> 4;
  const int xr = (lane & 7) << 4;
  int aOff[4];
#pragma unroll
  for (int m = 0; m < 4; ++m) aOff[m] = (m * 16 + ln15) * 128 + ((lg * 16) ^ xr);
  const int bOff = (wave * 16 + ln15) * 128 + ((lg * 16) ^ xr);

  f32x4 acc[4] = {};
  for (int kk = 0; kk < KD / 32; ++kk) {
    s16x8 av = *(const s16x8*)(aRow + kk * 32 + kq * 8);
    s16x8 bv = *(const s16x8*)(bRow + kk * 32 + kq * 8);
    __syncthreads();
    *(s16x8*)(As + dstOff) = av;
    *(s16x8*)(Bs + dstOff) = bv;
    __syncthreads();
    s16x8 bf = *(const s16x8*)(Bs + bOff);
#pragma unroll
    for (int m = 0; m < 4; ++m) {
      s16x8 af = *(const s16x8*)(As + aOff[m]);
      acc[m] = mfma_bf16(af, bf, acc[m]);
    }
  }

  const int colg = c0 + wave * 16 + ln15;
  float bv = 0.f;
  if (OUTF32) bv = biasv[colg];
#pragma unroll
  for (int m = 0; m < 4; ++m) {
#pragma unroll
    for (int rr = 0; rr < 4; ++rr) {
      int rowg = r0 + m * 16 + lg * 4 + rr;
      if (OUTF32) Cf[(size_t)rowg * NT + colg] = acc[m][rr] + bv;
      else        Cb[(size_t)rowg * NT + colg] = f2bf(acc[m][rr]);
    }
  }
}

struct FastTag { static constexpr bool fast = true;  };
struct SafeTag { static constexpr bool fast = false; };

// ---- persistent recurrence (R12, best proven): 512-thr wgs, 8-wg XCD groups ----
// 64 wgs launched; role: bg=bid&7 (<4 else exit), cs=bid>>3 (0..7, 128 cols each).
// Under round-robin a group's 8 wgs (bids == bg mod 8) share one XCD -> FAST
// mode (sc0, L2-coherent) after registration check; else SAFE (sc0sc1, L3).
// Proven pieces: V_w pinned in 128 VGPR/wave (R5); swapped MFMA mapping + ONE
// 8B produce (R8/R9); per-wave monotonic epoch flags, busy-poll lane-parallel
// (R10, 7x hang-free); XCD-local L2 exchange (R11); 2 waves/SIMD + fully
// conflict-free (row&15)<<4 LDS swizzle (R12: SQ_LDS_BANK_CONFLICT == 0).
__global__ __launch_bounds__(512, 1) void k_rec(
    const unsigned short* __restrict__ vwb,   // [H][H] bf16
    const unsigned short* __restrict__ ux,    // [B][L][H] bf16
    unsigned short* __restrict__ ring,        // [2][B][H] bf16
    unsigned short* __restrict__ hs,          // [B][L][H] bf16
    const float* __restrict__ alpha, const float* __restrict__ beta1,
    const float* __restrict__ beta2, const float* __restrict__ bias,
    float* __restrict__ out, int* flags, int* xcdtab)
{
  __shared__ __align__(16) unsigned char hlds[2][16 * 2048];   // 2 x 32 KiB
  __shared__ int smode;

  const int bid = blockIdx.x;
  const int bg = bid & 7, cs = bid >> 3;    // batch-group, col-slice (128 cols)
  if (bg >= 4) return;                      // spare wgs exit
  const int tid = threadIdx.x;
  const int wave = tid >> 6, lane = tid & 63;
  const int ln15 = lane & 15, lg = lane >> 4;
  const int b0 = bg * 16;
  const int colbase = cs * 128 + wave * 16 + lg * 4;
  const int myb = b0 + ln15;

  // ---- one-time registration + mode select ----
  int* gxt = xcdtab + bg * 16;
  if (tid == 0) {
    unsigned myxcd;
    asm volatile("s_getreg_b32 %0, hwreg(HW_REG_XCC_ID)" : "=s"(myxcd));
    myxcd &= 15u;
    __hip_atomic_store(&gxt[cs], (int)myxcd, __ATOMIC_RELAXED, __HIP_MEMORY_SCOPE_SYSTEM);
    int first = -1; bool same = true;
    for (int i = 0; i < 8;) {
      int v = __hip_atomic_load(&gxt[i], __ATOMIC_RELAXED, __HIP_MEMORY_SCOPE_SYSTEM);
      if (v == -1) { __builtin_amdgcn_s_sleep(8); continue; }
      if (first == -1) first = v; else if (v != first) same = false;
      ++i;
    }
    smode = same ? 1 : 0;
  }
  __syncthreads();
  const bool fastmode = (smode != 0);

  // A-operand resident: breg[kc] lane l = V_w[colrow][kc*32+(l>>4)*8..+8]
  s16x8 breg[32];
  {
    const unsigned short* vrow = vwb + (size_t)(cs * 128 + wave * 16 + ln15) * CH + lg * 8;
#pragma unroll
    for (int kc = 0; kc < 32; ++kc) breg[kc] = *(const s16x8*)(vrow + kc * 32);
  }
#pragma unroll
  for (int kc = 0; kc < 32; ++kc) asm volatile("" : "+v"(breg[kc]));  // pin (R5 win)

  const float4 alv = *(const float4*)(alpha + colbase);
  const float4 b1v = *(const float4*)(beta1 + colbase);
  const float4 b2v = *(const float4*)(beta2 + colbase);
  const float4 biv = *(const float4*)(bias  + colbase);

  __amdgpu_buffer_rsrc_t rsrd = __builtin_amdgcn_make_buffer_rsrc(
      (void*)ring, (short)0, (int)(2u * SLOT), 0x00020000);

  int* gflags = flags + bg * 64;            // 64 wave-flags per group (8 wgs x 8 waves)
  const int myflag = cs * 8 + wave;

  // staging: 512 threads x 4 chunks x 16B = 32 KiB slice
  // LDS identity: hlds[row][col ^ ((row&15)<<4)] = ring_slot[b0+row][col]
  int sRow[4], sCol[4];
#pragma unroll
  for (int i = 0; i < 4; ++i) {
    const int L = i * 8192 + tid * 16;
    sRow[i] = L >> 11;
    sCol[i] = (L & 2047) ^ ((sRow[i] & 15) << 4);
  }
  const unsigned stgBase = (unsigned)(b0 * 2048);

  // fragment reads (B = h): row ln15, chunk (lg*16 + kc*64) ^ (ln15<<4)
  // -> for fixed (lg,kc) the 16 ln15 lanes hit 16 DISTINCT 16B slots: conflict-free
  const int fBase = ln15 * 2048;
  const int fXor  = ln15 << 4;
  const unsigned cellOff = (unsigned)(myb * 2048 + colbase * 2);

  s16x4 uxv = *(const s16x4*)(ux + ((size_t)myb * CL + 0) * CH + colbase);

  auto run = [&](auto tag) {
    constexpr int  AUX = decltype(tag)::fast ? 1 : 17;
    constexpr auto SCP = decltype(tag)::fast ? __HIP_MEMORY_SCOPE_AGENT
                                             : __HIP_MEMORY_SCOPE_SYSTEM;
    for (int t = 0; t < CL; ++t) {
      f32x4 vh = {};
      if (t > 0) {
        // busy-poll all 64 producer-wave flags, lane-parallel
        bool ok;
        do {
          int fv = __hip_atomic_load(&gflags[lane], __ATOMIC_RELAXED, SCP);
          ok = __all(fv >= t) != 0;
        } while (!ok);
        asm volatile("" ::: "memory");

        // stage h(t-1) slice from slot (t-1)&1 into LDS (4 chunks/thread)
        const unsigned roff = ((unsigned)((t - 1) & 1)) * SLOT + stgBase;
        s16x8 stg[4];
#pragma unroll
        for (int i = 0; i < 4; ++i) {
          auto raw = __builtin_amdgcn_raw_buffer_load_b128(
              rsrd, (int)(roff + i * 8192 + tid * 16), 0, AUX);
          stg[i] = __builtin_bit_cast(s16x8, raw);
        }
        unsigned char* lb = hlds[t & 1];
#pragma unroll
        for (int i = 0; i < 4; ++i)
          *(s16x8*)(lb + sRow[i] * 2048 + sCol[i]) = stg[i];
        __syncthreads();                    // the ONE join per step

        // fragments + MFMA, A=V_w (resident), B=h, 4 chains
        f32x4 a0 = {}, a1 = {}, a2 = {}, a3 = {};
#pragma unroll
        for (int kc = 0; kc < 32; kc += 4) {
          s16x8 f0 = *(const s16x8*)(lb + fBase + ((lg * 16 + kc * 64)       ^ fXor));
          s16x8 f1 = *(const s16x8*)(lb + fBase + ((lg * 16 + kc * 64 + 64)  ^ fXor));
          s16x8 f2 = *(const s16x8*)(lb + fBase + ((lg * 16 + kc * 64 + 128) ^ fXor));
          s16x8 f3 = *(const s16x8*)(lb + fBase + ((lg * 16 + kc * 64 + 192) ^ fXor));
          a0 = mfma_bf16(breg[kc],     f0, a0);
          a1 = mfma_bf16(breg[kc + 1], f1, a1);
          a2 = mfma_bf16(breg[kc + 2], f2, a2);
          a3 = mfma_bf16(breg[kc + 3], f3, a3);
        }
        vh = (a0 + a1) + (a2 + a3);
      }

      // pointwise
      float hnv[4]; unsigned short hbv[4];
#pragma unroll
      for (int rr = 0; rr < 4; ++rr) {
        const float u = bf2f((unsigned short)uxv[rr]);
        const float v = vh[rr];
        const float mm = (&alv.x)[rr] * (v * u) + (&b1v.x)[rr] * v +
                         (&b2v.x)[rr] * u + (&biv.x)[rr];
        hnv[rr] = fast_tanh(mm);
        hbv[rr] = f2bf(hnv[rr]);
      }

      const unsigned long long pk = (unsigned long long)hbv[0]
                                  | ((unsigned long long)hbv[1] << 16)
                                  | ((unsigned long long)hbv[2] << 32)
                                  | ((unsigned long long)hbv[3] << 48);

      if (t < CL - 1) {
        // produce: ONE 8B store into slot t&1
        unsigned long long* hp = (unsigned long long*)
            ((char*)ring + (size_t)(t & 1) * SLOT + cellOff);
        __hip_atomic_store(hp, pk, __ATOMIC_RELAXED, SCP);
        // wave-level release: drain produce, then publish wave flag
        asm volatile("s_waitcnt vmcnt(0)" ::: "memory");
        if (lane == 0)
          __hip_atomic_store(&gflags[myflag], t + 1, __ATOMIC_RELAXED, SCP);
        // off critical path: hs persist + next ux prefetch (normal cached)
        *(unsigned long long*)(hs + ((size_t)myb * CL + t) * CH + colbase) = pk;
        uxv = *(const s16x4*)(ux + ((size_t)myb * CL + (t + 1)) * CH + colbase);
      } else {
        *(unsigned long long*)(hs + ((size_t)myb * CL + t) * CH + colbase) = pk;
        float4 o; o.x = hnv[0]; o.y = hnv[1]; o.z = hnv[2]; o.w = hnv[3];
        *(float4*)(out + LOGN + (size_t)myb * CH + colbase) = o;
      }
    }
  };
  if (fastmode) run(FastTag{}); else run(SafeTag{});
}

extern "C" void kernel_launch(void* const* d_in, const int* in_sizes, int n_in,
                              void* d_out, int out_size, void* d_ws, size_t ws_size,
                              hipStream_t stream) {
  const int*   x     = (const int*)  d_in[0];
  const float* emb   = (const float*)d_in[1];
  const float* Uw    = (const float*)d_in[2];
  const float* Vw    = (const float*)d_in[3];
  const float* alpha = (const float*)d_in[4];
  const float* beta1 = (const float*)d_in[5];
  const float* beta2 = (const float*)d_in[6];
  const float* bias  = (const float*)d_in[7];
  const float* decw  = (const float*)d_in[8];
  const float* decb  = (const float*)d_in[9];
  float* out = (float*)d_out;
  char*  ws  = (char*)d_ws;

  int*            flags = (int*)(ws + WS_BAR);
  int*            xcdt  = (int*)(ws + WS_XCDT);
  unsigned short* ring  = (unsigned short*)(ws + WS_RING);
  unsigned short* embb  = (unsigned short*)(ws + WS_EMBB);
  unsigned short* uwb   = (unsigned short*)(ws + WS_UWB);
  unsigned short* vwb   = (unsigned short*)(ws + WS_VWB);
  unsigned short* dwb   = (unsigned short*)(ws + WS_DECWB);
  unsigned short* uxb   = (unsigned short*)(ws + WS_UX);
  unsigned short* hsb   = (unsigned short*)(ws + WS_HS);

  (void)hipMemsetAsync(ws + WS_BAR, 0, 1024, stream);        // epoch flags = 0
  (void)hipMemsetAsync(ws + WS_XCDT, 0xFF, 256, stream);     // xcd table = -1

  k_convert<<<1920, 256, 0, stream>>>(emb, Uw, Vw, decw, embb, uwb, vwb, dwb);

  k_gemm<CE, CH, true, false><<<dim3(CBL / 64, CH / 64), 256, 0, stream>>>(
      embb, x, uwb, nullptr, uxb, nullptr);

  k_rec<<<64, 512, 0, stream>>>(vwb, uxb, ring, hsb, alpha, beta1, beta2, bias,
                                out, flags, xcdt);

  k_gemm<CH, CV, false, true><<<dim3(CBL / 64, CV / 64), 256, 0, stream>>>(
      hsb, nullptr, dwb, decb, nullptr, out);
}

// Round 18
// 1421.681 us; speedup vs baseline: 3.8402x; 1.1608x over previous
//
#include <hip/hip_runtime.h>

#define DI __device__ __forceinline__

typedef short s16x4 __attribute__((ext_vector_type(4)));
typedef short s16x8 __attribute__((ext_vector_type(8)));
typedef float f32x4 __attribute__((ext_vector_type(4)));

constexpr int CB = 64, CL = 512, CV = 256, CE = 512, CH = 1024;
constexpr int CBL = CB * CL;                // 32768
constexpr size_t LOGN = (size_t)CBL * CV;   // 8388608 floats of logits
constexpr unsigned SLOT = (unsigned)CB * CH * 2;   // 128 KiB per ring slot

// ---- workspace layout (bytes) ----
constexpr size_t WS_BAR   = 0;                              // flags: 4 bgs x 64 ints (1 KiB)
constexpr size_t WS_XCDT  = 1024;                           // xcd table: 4 x 16 ints
constexpr size_t WS_RING  = 4096;                           // 2-slot ring: 256 KiB
constexpr size_t WS_EMBB  = WS_RING + 2u*SLOT;              // emb bf16   256*512*2
constexpr size_t WS_UWB   = WS_EMBB + (size_t)CV*CE*2;      // U_w bf16   1024*512*2
constexpr size_t WS_VWB   = WS_UWB  + (size_t)CH*CE*2;      // V_w bf16   1024*1024*2
constexpr size_t WS_DECWB = WS_VWB  + (size_t)CH*CH*2;      // dec_w bf16 256*1024*2
constexpr size_t WS_UX    = WS_DECWB+ (size_t)CV*CH*2;      // Ux bf16    32768*1024*2
constexpr size_t WS_HS    = WS_UX   + (size_t)CBL*CH*2;     // hs bf16    32768*1024*2

DI unsigned short f2bf(float f) {            // RNE f32 -> bf16
  unsigned u = __float_as_uint(f);
  u += 0x7FFFu + ((u >> 16) & 1u);
  return (unsigned short)(u >> 16);
}
DI float bf2f(unsigned short h) { return __uint_as_float(((unsigned)h) << 16); }

DI f32x4 mfma_bf16(s16x8 a, s16x8 b, f32x4 c) {
  return __builtin_amdgcn_mfma_f32_16x16x32_bf16(a, b, c, 0, 0, 0);
}

DI float fast_tanh(float x) {
  float a = fminf(fabsf(x), 20.0f);
  float e = __expf(-2.0f * a);
  float r = (1.0f - e) / (1.0f + e);
  return __builtin_copysignf(r, x);
}

// ---------------- convert f32 weights -> bf16 in ws ----------------
__global__ __launch_bounds__(256) void k_convert(
    const float* __restrict__ emb, const float* __restrict__ uw,
    const float* __restrict__ vw,  const float* __restrict__ dw,
    unsigned short* __restrict__ embb, unsigned short* __restrict__ uwb,
    unsigned short* __restrict__ vwb,  unsigned short* __restrict__ dwb)
{
  int i = (blockIdx.x * 256 + threadIdx.x) * 4;   // 1966080 elems total, grid exact
  const float* s; unsigned short* d; int off;
  if      (i < 131072)  { s = emb; d = embb; off = i; }
  else if (i < 655360)  { s = uw;  d = uwb;  off = i - 131072; }
  else if (i < 1703936) { s = vw;  d = vwb;  off = i - 655360; }
  else                  { s = dw;  d = dwb;  off = i - 1703936; }
  float4 v = *(const float4*)(s + off);
  ushort4 o; o.x = f2bf(v.x); o.y = f2bf(v.y); o.z = f2bf(v.z); o.w = f2bf(v.w);
  *(ushort4*)(d + off) = o;
}

// -------- 128x128-tile bf16 MFMA GEMM: C[r,n] = sum_k A[r,k]*B[n,k] --------
// 256 thr = 4 waves; wave (wm,wn) owns a 64x64 quadrant, acc[4][4] of 16x16.
// Reg-staged LDS, pitch 40 elems (80B): fragment-read banking ~2-way (free).
// 64 MFMA per wg per K-step (4x the old 64^2 tile's 16) -> 4x less barrier
// and staging overhead per FLOP. Accumulation order per output identical to
// the old kernel -> bit-identical results.
template<int KD, int NT, bool GATHER, bool OUTF32>
__global__ __launch_bounds__(256) void k_gemm(
    const unsigned short* __restrict__ Asrc,
    const int* __restrict__ xidx,
    const unsigned short* __restrict__ Bsrc,   // [NT][KD] rows are output cols
    const float* __restrict__ biasv,
    unsigned short* __restrict__ Cb,
    float* __restrict__ Cf)
{
  constexpr int PITCH = 40;                 // elems per LDS row (32 data + 8 pad)
  __shared__ unsigned short As[128 * PITCH];   // 10 KiB
  __shared__ unsigned short Bs[128 * PITCH];   // 10 KiB
  __shared__ int xs[128];

  const int tid = threadIdx.x;
  const int r0 = blockIdx.x * 128, c0 = blockIdx.y * 128;

  if (GATHER) {
    if (tid < 128) xs[tid] = xidx[r0 + tid];
    __syncthreads();
  }

  // staging: thread t -> row t>>1, 32B chunk at elem ((t&1)*2)*8
  const int sr = tid >> 1, ss = (tid & 1) * 16;   // elem offset within row
  const unsigned short* aRow =
      (GATHER ? (Asrc + (size_t)xs[sr] * KD) : (Asrc + (size_t)(r0 + sr) * KD)) + ss;
  const unsigned short* bRow = Bsrc + (size_t)(c0 + sr) * KD + ss;
  unsigned short* aDst = As + sr * PITCH + ss;
  unsigned short* bDst = Bs + sr * PITCH + ss;

  const int wave = tid >> 6, lane = tid & 63;
  const int ln15 = lane & 15, lg = lane >> 4;
  const int wm = wave >> 1, wn = wave & 1;        // 64x64 quadrant

  // fragment base offsets (elems): row = quad + m*16 + ln15, k-chunk lg*8
  int aOff[4], bOff[4];
#pragma unroll
  for (int m = 0; m < 4; ++m) aOff[m] = (wm * 64 + m * 16 + ln15) * PITCH + lg * 8;
#pragma unroll
  for (int n = 0; n < 4; ++n) bOff[n] = (wn * 64 + n * 16 + ln15) * PITCH + lg * 8;

  f32x4 acc[4][4] = {};

  for (int kk = 0; kk < KD / 32; ++kk) {
    s16x8 av0 = *(const s16x8*)(aRow + kk * 32);
    s16x8 av1 = *(const s16x8*)(aRow + kk * 32 + 8);
    s16x8 bv0 = *(const s16x8*)(bRow + kk * 32);
    s16x8 bv1 = *(const s16x8*)(bRow + kk * 32 + 8);
    __syncthreads();                       // prior iter's ds_reads done
    *(s16x8*)(aDst)     = av0;
    *(s16x8*)(aDst + 8) = av1;
    *(s16x8*)(bDst)     = bv0;
    *(s16x8*)(bDst + 8) = bv1;
    __syncthreads();

    s16x8 bf[4];
#pragma unroll
    for (int n = 0; n < 4; ++n) bf[n] = *(const s16x8*)(Bs + bOff[n]);
#pragma unroll
    for (int m = 0; m < 4; ++m) {
      s16x8 af = *(const s16x8*)(As + aOff[m]);
#pragma unroll
      for (int n = 0; n < 4; ++n)
        acc[m][n] = mfma_bf16(af, bf[n], acc[m][n]);
    }
  }

  // epilogue: D row = A-frag rows, D col = B-frag rows;
  // lane mapping col=lane&15, row=(lane>>4)*4+reg (m89-verified)
#pragma unroll
  for (int m = 0; m < 4; ++m) {
#pragma unroll
    for (int n = 0; n < 4; ++n) {
      const int colg = c0 + wn * 64 + n * 16 + ln15;
      float bv = 0.f;
      if (OUTF32) bv = biasv[colg];
#pragma unroll
      for (int rr = 0; rr < 4; ++rr) {
        const int rowg = r0 + wm * 64 + m * 16 + lg * 4 + rr;
        if (OUTF32) Cf[(size_t)rowg * NT + colg] = acc[m][n][rr] + bv;
        else        Cb[(size_t)rowg * NT + colg] = f2bf(acc[m][n][rr]);
      }
    }
  }
}

struct FastTag { static constexpr bool fast = true;  };
struct SafeTag { static constexpr bool fast = false; };

// ---- persistent recurrence (R12, best proven): 512-thr wgs, 8-wg XCD groups ----
__global__ __launch_bounds__(512, 1) void k_rec(
    const unsigned short* __restrict__ vwb,   // [H][H] bf16
    const unsigned short* __restrict__ ux,    // [B][L][H] bf16
    unsigned short* __restrict__ ring,        // [2][B][H] bf16
    unsigned short* __restrict__ hs,          // [B][L][H] bf16
    const float* __restrict__ alpha, const float* __restrict__ beta1,
    const float* __restrict__ beta2, const float* __restrict__ bias,
    float* __restrict__ out, int* flags, int* xcdtab)
{
  __shared__ __align__(16) unsigned char hlds[2][16 * 2048];   // 2 x 32 KiB
  __shared__ int smode;

  const int bid = blockIdx.x;
  const int bg = bid & 7, cs = bid >> 3;    // batch-group, col-slice (128 cols)
  if (bg >= 4) return;                      // spare wgs exit
  const int tid = threadIdx.x;
  const int wave = tid >> 6, lane = tid & 63;
  const int ln15 = lane & 15, lg = lane >> 4;
  const int b0 = bg * 16;
  const int colbase = cs * 128 + wave * 16 + lg * 4;
  const int myb = b0 + ln15;

  // ---- one-time registration + mode select ----
  int* gxt = xcdtab + bg * 16;
  if (tid == 0) {
    unsigned myxcd;
    asm volatile("s_getreg_b32 %0, hwreg(HW_REG_XCC_ID)" : "=s"(myxcd));
    myxcd &= 15u;
    __hip_atomic_store(&gxt[cs], (int)myxcd, __ATOMIC_RELAXED, __HIP_MEMORY_SCOPE_SYSTEM);
    int first = -1; bool same = true;
    for (int i = 0; i < 8;) {
      int v = __hip_atomic_load(&gxt[i], __ATOMIC_RELAXED, __HIP_MEMORY_SCOPE_SYSTEM);
      if (v == -1) { __builtin_amdgcn_s_sleep(8); continue; }
      if (first == -1) first = v; else if (v != first) same = false;
      ++i;
    }
    smode = same ? 1 : 0;
  }
  __syncthreads();
  const bool fastmode = (smode != 0);

  // A-operand resident: breg[kc] lane l = V_w[colrow][kc*32+(l>>4)*8..+8]
  s16x8 breg[32];
  {
    const unsigned short* vrow = vwb + (size_t)(cs * 128 + wave * 16 + ln15) * CH + lg * 8;
#pragma unroll
    for (int kc = 0; kc < 32; ++kc) breg[kc] = *(const s16x8*)(vrow + kc * 32);
  }
#pragma unroll
  for (int kc = 0; kc < 32; ++kc) asm volatile("" : "+v"(breg[kc]));  // pin (R5 win)

  const float4 alv = *(const float4*)(alpha + colbase);
  const float4 b1v = *(const float4*)(beta1 + colbase);
  const float4 b2v = *(const float4*)(beta2 + colbase);
  const float4 biv = *(const float4*)(bias  + colbase);

  __amdgpu_buffer_rsrc_t rsrd = __builtin_amdgcn_make_buffer_rsrc(
      (void*)ring, (short)0, (int)(2u * SLOT), 0x00020000);

  int* gflags = flags + bg * 64;            // 64 wave-flags per group (8 wgs x 8 waves)
  const int myflag = cs * 8 + wave;

  // staging: 512 threads x 4 chunks x 16B = 32 KiB slice
  // LDS identity: hlds[row][col ^ ((row&15)<<4)] = ring_slot[b0+row][col]
  int sRow[4], sCol[4];
#pragma unroll
  for (int i = 0; i < 4; ++i) {
    const int L = i * 8192 + tid * 16;
    sRow[i] = L >> 11;
    sCol[i] = (L & 2047) ^ ((sRow[i] & 15) << 4);
  }
  const unsigned stgBase = (unsigned)(b0 * 2048);

  // fragment reads (B = h): row ln15, chunk (lg*16 + kc*64) ^ (ln15<<4)
  const int fBase = ln15 * 2048;
  const int fXor  = ln15 << 4;
  const unsigned cellOff = (unsigned)(myb * 2048 + colbase * 2);

  s16x4 uxv = *(const s16x4*)(ux + ((size_t)myb * CL + 0) * CH + colbase);

  auto run = [&](auto tag) {
    constexpr int  AUX = decltype(tag)::fast ? 1 : 17;
    constexpr auto SCP = decltype(tag)::fast ? __HIP_MEMORY_SCOPE_AGENT
                                             : __HIP_MEMORY_SCOPE_SYSTEM;
    for (int t = 0; t < CL; ++t) {
      f32x4 vh = {};
      if (t > 0) {
        // busy-poll all 64 producer-wave flags, lane-parallel
        bool ok;
        do {
          int fv = __hip_atomic_load(&gflags[lane], __ATOMIC_RELAXED, SCP);
          ok = __all(fv >= t) != 0;
        } while (!ok);
        asm volatile("" ::: "memory");

        // stage h(t-1) slice from slot (t-1)&1 into LDS (4 chunks/thread)
        const unsigned roff = ((unsigned)((t - 1) & 1)) * SLOT + stgBase;
        s16x8 stg[4];
#pragma unroll
        for (int i = 0; i < 4; ++i) {
          auto raw = __builtin_amdgcn_raw_buffer_load_b128(
              rsrd, (int)(roff + i * 8192 + tid * 16), 0, AUX);
          stg[i] = __builtin_bit_cast(s16x8, raw);
        }
        unsigned char* lb = hlds[t & 1];
#pragma unroll
        for (int i = 0; i < 4; ++i)
          *(s16x8*)(lb + sRow[i] * 2048 + sCol[i]) = stg[i];
        __syncthreads();                    // the ONE join per step

        // fragments + MFMA, A=V_w (resident), B=h, 4 chains
        f32x4 a0 = {}, a1 = {}, a2 = {}, a3 = {};
#pragma unroll
        for (int kc = 0; kc < 32; kc += 4) {
          s16x8 f0 = *(const s16x8*)(lb + fBase + ((lg * 16 + kc * 64)       ^ fXor));
          s16x8 f1 = *(const s16x8*)(lb + fBase + ((lg * 16 + kc * 64 + 64)  ^ fXor));
          s16x8 f2 = *(const s16x8*)(lb + fBase + ((lg * 16 + kc * 64 + 128) ^ fXor));
          s16x8 f3 = *(const s16x8*)(lb + fBase + ((lg * 16 + kc * 64 + 192) ^ fXor));
          a0 = mfma_bf16(breg[kc],     f0, a0);
          a1 = mfma_bf16(breg[kc + 1], f1, a1);
          a2 = mfma_bf16(breg[kc + 2], f2, a2);
          a3 = mfma_bf16(breg[kc + 3], f3, a3);
        }
        vh = (a0 + a1) + (a2 + a3);
      }

      // pointwise
      float hnv[4]; unsigned short hbv[4];
#pragma unroll
      for (int rr = 0; rr < 4; ++rr) {
        const float u = bf2f((unsigned short)uxv[rr]);
        const float v = vh[rr];
        const float mm = (&alv.x)[rr] * (v * u) + (&b1v.x)[rr] * v +
                         (&b2v.x)[rr] * u + (&biv.x)[rr];
        hnv[rr] = fast_tanh(mm);
        hbv[rr] = f2bf(hnv[rr]);
      }

      const unsigned long long pk = (unsigned long long)hbv[0]
                                  | ((unsigned long long)hbv[1] << 16)
                                  | ((unsigned long long)hbv[2] << 32)
                                  | ((unsigned long long)hbv[3] << 48);

      if (t < CL - 1) {
        // produce: ONE 8B store into slot t&1
        unsigned long long* hp = (unsigned long long*)
            ((char*)ring + (size_t)(t & 1) * SLOT + cellOff);
        __hip_atomic_store(hp, pk, __ATOMIC_RELAXED, SCP);
        // wave-level release: drain produce, then publish wave flag
        asm volatile("s_waitcnt vmcnt(0)" ::: "memory");
        if (lane == 0)
          __hip_atomic_store(&gflags[myflag], t + 1, __ATOMIC_RELAXED, SCP);
        // off critical path: hs persist + next ux prefetch (normal cached)
        *(unsigned long long*)(hs + ((size_t)myb * CL + t) * CH + colbase) = pk;
        uxv = *(const s16x4*)(ux + ((size_t)myb * CL + (t + 1)) * CH + colbase);
      } else {
        *(unsigned long long*)(hs + ((size_t)myb * CL + t) * CH + colbase) = pk;
        float4 o; o.x = hnv[0]; o.y = hnv[1]; o.z = hnv[2]; o.w = hnv[3];
        *(float4*)(out + LOGN + (size_t)myb * CH + colbase) = o;
      }
    }
  };
  if (fastmode) run(FastTag{}); else run(SafeTag{});
}

extern "C" void kernel_launch(void* const* d_in, const int* in_sizes, int n_in,
                              void* d_out, int out_size, void* d_ws, size_t ws_size,
                              hipStream_t stream) {
  const int*   x     = (const int*)  d_in[0];
  const float* emb   = (const float*)d_in[1];
  const float* Uw    = (const float*)d_in[2];
  const float* Vw    = (const float*)d_in[3];
  const float* alpha = (const float*)d_in[4];
  const float* beta1 = (const float*)d_in[5];
  const float* beta2 = (const float*)d_in[6];
  const float* bias  = (const float*)d_in[7];
  const float* decw  = (const float*)d_in[8];
  const float* decb  = (const float*)d_in[9];
  float* out = (float*)d_out;
  char*  ws  = (char*)d_ws;

  int*            flags = (int*)(ws + WS_BAR);
  int*            xcdt  = (int*)(ws + WS_XCDT);
  unsigned short* ring  = (unsigned short*)(ws + WS_RING);
  unsigned short* embb  = (unsigned short*)(ws + WS_EMBB);
  unsigned short* uwb   = (unsigned short*)(ws + WS_UWB);
  unsigned short* vwb   = (unsigned short*)(ws + WS_VWB);
  unsigned short* dwb   = (unsigned short*)(ws + WS_DECWB);
  unsigned short* uxb   = (unsigned short*)(ws + WS_UX);
  unsigned short* hsb   = (unsigned short*)(ws + WS_HS);

  (void)hipMemsetAsync(ws + WS_BAR, 0, 1024, stream);        // epoch flags = 0
  (void)hipMemsetAsync(ws + WS_XCDT, 0xFF, 256, stream);     // xcd table = -1

  k_convert<<<1920, 256, 0, stream>>>(emb, Uw, Vw, decw, embb, uwb, vwb, dwb);

  // Ux: M=32768 (gathered emb rows), N=1024, K=512 — 128^2 tiles
  k_gemm<CE, CH, true, false><<<dim3(CBL / 128, CH / 128), 256, 0, stream>>>(
      embb, x, uwb, nullptr, uxb, nullptr);

  k_rec<<<64, 512, 0, stream>>>(vwb, uxb, ring, hsb, alpha, beta1, beta2, bias,
                                out, flags, xcdt);

  // logits: M=32768, N=256, K=1024 — 128^2 tiles
  k_gemm<CH, CV, false, true><<<dim3(CBL / 128, CV / 128), 256, 0, stream>>>(
      hsb, nullptr, dwb, decb, nullptr, out);
}